// Round 1
// baseline (97.509 us; speedup 1.0000x reference)
//
#include <hip/hip_runtime.h>

// LIF spike forward: x [B=64, T=8, C=128, H=32, W=32] fp32 -> spikes (0/1) fp32.
// Recurrence per neuron over t: mem = mem*0.5 + x_t; s = (mem-1>0); mem *= (1-s).
// Memory-bound: 256 MiB read + 256 MiB write.

#define T_STEPS 8
#define B_DIM   64
#define CHW     131072   // 128*32*32, contiguous per (b,t)
#define CHW4    (CHW/4)  // 32768 float4 per (b,t)

__global__ __launch_bounds__(256)
void AI_LIFSpike_kernel(const float4* __restrict__ x, float4* __restrict__ out) {
    int i = blockIdx.x * blockDim.x + threadIdx.x;   // 0 .. B*CHW4-1
    int b   = i >> 15;            // i / CHW4
    int c4  = i & (CHW4 - 1);     // i % CHW4
    long base = (long)b * (T_STEPS * CHW4) + c4;

    float mx = 0.f, my = 0.f, mz = 0.f, mw = 0.f;
#pragma unroll
    for (int t = 0; t < T_STEPS; ++t) {
        float4 xt = x[base + (long)t * CHW4];
        mx = mx * 0.5f + xt.x;
        my = my * 0.5f + xt.y;
        mz = mz * 0.5f + xt.z;
        mw = mw * 0.5f + xt.w;
        float4 s;
        s.x = (mx - 1.0f > 0.0f) ? 1.0f : 0.0f;
        s.y = (my - 1.0f > 0.0f) ? 1.0f : 0.0f;
        s.z = (mz - 1.0f > 0.0f) ? 1.0f : 0.0f;
        s.w = (mw - 1.0f > 0.0f) ? 1.0f : 0.0f;
        // hard reset
        mx = (s.x != 0.0f) ? 0.0f : mx;
        my = (s.y != 0.0f) ? 0.0f : my;
        mz = (s.z != 0.0f) ? 0.0f : mz;
        mw = (s.w != 0.0f) ? 0.0f : mw;
        out[base + (long)t * CHW4] = s;
    }
}

extern "C" void kernel_launch(void* const* d_in, const int* in_sizes, int n_in,
                              void* d_out, int out_size, void* d_ws, size_t ws_size,
                              hipStream_t stream) {
    const float4* x = (const float4*)d_in[0];
    float4* out = (float4*)d_out;
    const int total_vec = B_DIM * CHW4;          // 2,097,152 threads
    dim3 block(256);
    dim3 grid(total_vec / 256);                  // 8192 blocks
    AI_LIFSpike_kernel<<<grid, block, 0, stream>>>(x, out);
}

// Round 3
// 89.079 us; speedup vs baseline: 1.0946x; 1.0946x over previous
//
#include <hip/hip_runtime.h>

// LIF spike forward: x [B=64, T=8, C=128, H=32, W=32] fp32 -> spikes (0/1) fp32.
// Recurrence per neuron over t: mem = mem*0.5 + x_t; s = (mem-1>0); mem *= (1-s).
// Memory-bound: 256 MiB read + 256 MiB write, zero reuse -> non-temporal streams.

#define T_STEPS 8
#define B_DIM   64
#define CHW     131072   // 128*32*32, contiguous per (b,t)
#define CHW4    (CHW/4)  // 32768 float4 per (b,t)

typedef float f32x4 __attribute__((ext_vector_type(4)));

__global__ __launch_bounds__(256)
void AI_LIFSpike_kernel(const f32x4* __restrict__ x, f32x4* __restrict__ out) {
    int i = blockIdx.x * blockDim.x + threadIdx.x;   // 0 .. B*CHW4-1
    int b   = i >> 15;            // i / CHW4
    int c4  = i & (CHW4 - 1);     // i % CHW4
    long base = (long)b * (T_STEPS * CHW4) + c4;

    float mx = 0.f, my = 0.f, mz = 0.f, mw = 0.f;
#pragma unroll
    for (int t = 0; t < T_STEPS; ++t) {
        f32x4 xt = __builtin_nontemporal_load(&x[base + (long)t * CHW4]);
        mx = mx * 0.5f + xt.x;
        my = my * 0.5f + xt.y;
        mz = mz * 0.5f + xt.z;
        mw = mw * 0.5f + xt.w;
        f32x4 s;
        s.x = (mx - 1.0f > 0.0f) ? 1.0f : 0.0f;
        s.y = (my - 1.0f > 0.0f) ? 1.0f : 0.0f;
        s.z = (mz - 1.0f > 0.0f) ? 1.0f : 0.0f;
        s.w = (mw - 1.0f > 0.0f) ? 1.0f : 0.0f;
        // hard reset
        mx = (s.x != 0.0f) ? 0.0f : mx;
        my = (s.y != 0.0f) ? 0.0f : my;
        mz = (s.z != 0.0f) ? 0.0f : mz;
        mw = (s.w != 0.0f) ? 0.0f : mw;
        __builtin_nontemporal_store(s, &out[base + (long)t * CHW4]);
    }
}

extern "C" void kernel_launch(void* const* d_in, const int* in_sizes, int n_in,
                              void* d_out, int out_size, void* d_ws, size_t ws_size,
                              hipStream_t stream) {
    const f32x4* x = (const f32x4*)d_in[0];
    f32x4* out = (f32x4*)d_out;
    const int total_vec = B_DIM * CHW4;          // 2,097,152 threads
    dim3 block(256);
    dim3 grid(total_vec / 256);                  // 8192 blocks
    AI_LIFSpike_kernel<<<grid, block, 0, stream>>>(x, out);
}